// Round 4
// baseline (438.210 us; speedup 1.0000x reference)
//
#include <hip/hip_runtime.h>

#define BB 16
#define NN 38400
#define SS 7
#define TROWS 64   // rows per tile
#define XST 68     // LDS floats per row (17 granules of 16B)
#define BPB 112    // blocks per batch
#define TPB 600    // tiles per batch (38400/64)

__device__ __forceinline__ float wsum64(float v) {
#pragma unroll
  for (int off = 32; off > 0; off >>= 1) v += __shfl_xor(v, off);
  return v;
}

// ---------------------------------------------------------------------------
// Slot-side kernel: 112 blocks (one per (b,s)), 64 threads (lane = d).
// mode 0: init slots; mode 1: GRU+MLP update; mode 2: update + write out.
// ACCM is recovered from ACC: sum_n p*rstd*mean = (1/64) * sum_d ACC[s][d].
// ---------------------------------------------------------------------------
__global__ __launch_bounds__(64) void k_slot(
    int mode,
    const float* __restrict__ slots_init, const float* __restrict__ mu,
    const float* __restrict__ lsig,
    const float* __restrict__ ln_slot_g, const float* __restrict__ ln_slot_b,
    const float* __restrict__ ln_mlp_g, const float* __restrict__ ln_mlp_b,
    const float* __restrict__ ln_in_g, const float* __restrict__ ln_in_b,
    const float* __restrict__ Wq, const float* __restrict__ Wk,
    const float* __restrict__ Wv,
    const float* __restrict__ W_ih, const float* __restrict__ W_hh,
    const float* __restrict__ b_ih, const float* __restrict__ b_hh,
    const float* __restrict__ W1, const float* __restrict__ b1,
    const float* __restrict__ W2, const float* __restrict__ b2,
    float* __restrict__ slots, float* __restrict__ gqk,
    float* __restrict__ sc,
    float* __restrict__ ACC, float* __restrict__ Zg,
    float* __restrict__ out)
{
  const int bs = blockIdx.x;
  const int b = bs / SS, s = bs % SS;
  const int d = threadIdx.x;
  __shared__ float t0[64], t1[64], hh[128];

  float slot;
  if (mode == 0) {
    slot = mu[d] + __expf(lsig[d]) * slots_init[bs * 64 + d];
  } else {
    const float zv = Zg[b * 8 + s];
    const float ac = ACC[(b * 8 + s) * 64 + d];
    const float am = wsum64(ac) * (1.f / 64.f);  // = sum_n p*rstd*mean
    const float ubar = (ln_in_g[d] * (ac - am) + ln_in_b[d] * zv) / zv;
    t0[d] = ubar;
    __syncthreads();
    float upd = 0.f;
#pragma unroll
    for (int e = 0; e < 64; ++e) upd += t0[e] * Wv[d * 64 + e];
    const float sp = slots[bs * 64 + d];
    __syncthreads();
    t0[d] = upd;
    t1[d] = sp;
    __syncthreads();
    float s_r = b_ih[d] + b_hh[d];
    float s_z = b_ih[64 + d] + b_hh[64 + d];
    float i_n = b_ih[128 + d];
    float h_n = b_hh[128 + d];
#pragma unroll
    for (int e = 0; e < 64; ++e) {
      const float u = t0[e], p = t1[e];
      s_r += u * W_ih[d * 64 + e] + p * W_hh[d * 64 + e];
      s_z += u * W_ih[(64 + d) * 64 + e] + p * W_hh[(64 + d) * 64 + e];
      i_n += u * W_ih[(128 + d) * 64 + e];
      h_n += p * W_hh[(128 + d) * 64 + e];
    }
    const float rg = 1.f / (1.f + __expf(-s_r));
    const float zg = 1.f / (1.f + __expf(-s_z));
    const float ng = tanhf(i_n + rg * h_n);
    const float hv = (1.f - zg) * ng + zg * sp;
    const float mn = wsum64(hv) * (1.f / 64.f);
    const float dv = hv - mn;
    const float vr = wsum64(dv * dv) * (1.f / 64.f);
    const float rs = rsqrtf(vr + 1e-5f);
    const float mld = dv * rs * ln_mlp_g[d] + ln_mlp_b[d];
    __syncthreads();
    t0[d] = mld;
    __syncthreads();
    float h0 = b1[d], h1 = b1[64 + d];
#pragma unroll
    for (int e = 0; e < 64; ++e) {
      const float m = t0[e];
      h0 += m * W1[d * 64 + e];
      h1 += m * W1[(64 + d) * 64 + e];
    }
    hh[d] = fmaxf(h0, 0.f);
    hh[64 + d] = fmaxf(h1, 0.f);
    __syncthreads();
    float o = hv + b2[d];
#pragma unroll
    for (int j = 0; j < 128; ++j) o += hh[j] * W2[d * 128 + j];
    slot = o;
  }

  if (mode == 2) {
    out[bs * 64 + d] = slot;
    return;
  }
  slots[bs * 64 + d] = slot;

  // tail: LN_slot -> q -> gqk (scale & ln_in_g folded), sgq, cb
  const float mn = wsum64(slot) * (1.f / 64.f);
  const float dv = slot - mn;
  const float vr = wsum64(dv * dv) * (1.f / 64.f);
  const float rs = rsqrtf(vr + 1e-5f);
  const float sln = dv * rs * ln_slot_g[d] + ln_slot_b[d];
  __syncthreads();
  t0[d] = sln;
  __syncthreads();
  float qv = 0.f;
#pragma unroll
  for (int e = 0; e < 64; ++e) qv += t0[e] * Wq[d * 64 + e];
  __syncthreads();
  t1[d] = qv;
  __syncthreads();
  float qe = 0.f;
#pragma unroll
  for (int dd = 0; dd < 64; ++dd) qe += t1[dd] * Wk[dd * 64 + d];
  qe *= 0.125f;  // scale = D^-0.5
  const float gq = ln_in_g[d] * qe;
  gqk[(b * 8 + s) * 64 + d] = gq;
  const float sg = wsum64(gq);
  const float cb = wsum64(ln_in_b[d] * qe);
  if (d == 0) {
    sc[(b * 8 + s) * 2 + 0] = sg;
    sc[(b * 8 + s) * 2 + 1] = cb;
  }
  ACC[(b * 8 + s) * 64 + d] = 0.f;
  if (d == 0) Zg[b * 8 + s] = 0.f;
}

// ---------------------------------------------------------------------------
// Main kernel: 1792 blocks (112 per batch) x 256 threads. Each block strides
// over 5-6 64-row tiles of its batch. Per tile:
//   stage : 16KB coalesced float4 -> LDS rows of stride 68 (no swizzle math)
//   P1    : quad-per-row (lane owns 16 cols): 7 dots + LN stats, 2-step
//           shfl_xor reduce, softmax; q==0 writes p*rstd to pa[n][8]
//   P2    : lane = (n-residue, d-chunk): full-width b128 xs reads (all 64
//           lanes distinct 16B) + 4-addr broadcast b128 pa reads; 28 fma
//           into persistent acc[7][4]
// One flush per block: shfl + LDS-scratch reduce, 448+28 atomics.
// ---------------------------------------------------------------------------
__global__ __launch_bounds__(256, 6) void k_main(
    const float* __restrict__ x,
    const float* __restrict__ gqk,  // [B][8][64]
    const float* __restrict__ sc,   // [B][8][2]
    float* __restrict__ ACC, float* __restrict__ Zg)
{
  __shared__ __align__(16) float xs[TROWS * XST];  // 17408 B
  __shared__ __align__(16) float pa[TROWS * 8];    // 2048 B
  __shared__ __align__(16) float qbs[512];         // 2048 B
  __shared__ float scs[16];

  const int t = threadIdx.x;
  const int lane = t & 63;
  const int w = t >> 6;
  const int b = blockIdx.x / BPB;
  const int kb = blockIdx.x % BPB;

  qbs[t] = gqk[b * 512 + t];
  qbs[t + 256] = gqk[b * 512 + t + 256];
  if (t < 16) scs[t] = sc[b * 16 + t];

  float acc[7][4];
#pragma unroll
  for (int s = 0; s < 7; ++s)
#pragma unroll
    for (int i = 0; i < 4; ++i) acc[s][i] = 0.f;
  float zac[7] = {0, 0, 0, 0, 0, 0, 0};

  const int r1 = t >> 2, q1 = t & 3;  // phase-1: row, quad-lane
  const int d4 = lane & 15;           // phase-2: d-chunk (cols 4*d4..+3)
  const int ne = lane >> 4;           // phase-2: n-residue 0..3

  for (int tile = kb; tile < TPB; tile += BPB) {
    // ---- load tile to regs (issues before barrier; hides under prev P2) ----
    const float4* src = reinterpret_cast<const float4*>(
        x + ((size_t)b * NN + (size_t)tile * TROWS) * 64);
    const float4 st0 = src[t];
    const float4 st1 = src[t + 256];
    const float4 st2 = src[t + 512];
    const float4 st3 = src[t + 768];
    __syncthreads();  // prev tile's P2 reads done before overwrite
    {
      int f = t;
      *reinterpret_cast<float4*>(&xs[(f >> 4) * XST + (f & 15) * 4]) = st0;
      f = t + 256;
      *reinterpret_cast<float4*>(&xs[(f >> 4) * XST + (f & 15) * 4]) = st1;
      f = t + 512;
      *reinterpret_cast<float4*>(&xs[(f >> 4) * XST + (f & 15) * 4]) = st2;
      f = t + 768;
      *reinterpret_cast<float4*>(&xs[(f >> 4) * XST + (f & 15) * 4]) = st3;
    }
    __syncthreads();

    // ---- phase 1: quad-per-row ----
    {
      const float* xrow = &xs[r1 * XST + q1 * 16];
      float lg[7] = {0, 0, 0, 0, 0, 0, 0};
      float sum = 0.f, sq = 0.f;
#pragma unroll
      for (int j = 0; j < 4; ++j) {
        const float4 v = *reinterpret_cast<const float4*>(&xrow[j * 4]);
        sum += v.x + v.y + v.z + v.w;
        sq = fmaf(v.x, v.x, fmaf(v.y, v.y, fmaf(v.z, v.z, fmaf(v.w, v.w, sq))));
#pragma unroll
        for (int s = 0; s < 7; ++s) {
          const float4 g = *reinterpret_cast<const float4*>(
              &qbs[s * 64 + q1 * 16 + j * 4]);
          lg[s] = fmaf(v.x, g.x,
                       fmaf(v.y, g.y, fmaf(v.z, g.z, fmaf(v.w, g.w, lg[s]))));
        }
      }
      // reduce across the quad (offsets 1,2 stay within the 4-lane group)
#pragma unroll
      for (int off = 1; off <= 2; off <<= 1) {
        sum += __shfl_xor(sum, off);
        sq += __shfl_xor(sq, off);
#pragma unroll
        for (int s = 0; s < 7; ++s) lg[s] += __shfl_xor(lg[s], off);
      }
      const float mean = sum * (1.f / 64.f);
      const float var = sq * (1.f / 64.f) - mean * mean;
      const float rstd = rsqrtf(var + 1e-5f);
      const float rm = rstd * mean;
      float mx = -1e30f;
#pragma unroll
      for (int s = 0; s < 7; ++s) {
        lg[s] = rstd * lg[s] - rm * scs[s * 2] + scs[s * 2 + 1];
        mx = fmaxf(mx, lg[s]);
      }
      float se = 0.f;
#pragma unroll
      for (int s = 0; s < 7; ++s) {
        lg[s] = __expf(lg[s] - mx);
        se += lg[s];
      }
      const float inv = 1.f / se;
      float pr[7];
#pragma unroll
      for (int s = 0; s < 7; ++s) {
        const float p = lg[s] * inv + 1e-8f;
        pr[s] = p * rstd;
        zac[s] += p;  // 4x replicated across quad; corrected at flush
      }
      if (q1 == 0) {
        const float4 w1 = {pr[0], pr[1], pr[2], pr[3]};
        const float4 w2 = {pr[4], pr[5], pr[6], 0.f};
        *reinterpret_cast<float4*>(&pa[r1 * 8]) = w1;
        *reinterpret_cast<float4*>(&pa[r1 * 8 + 4]) = w2;
      }
    }
    __syncthreads();

    // ---- phase 2: wave w covers n in [16w,16w+16), residue ne ----
#pragma unroll
    for (int n0 = 0; n0 < 16; n0 += 4) {
      const int n = w * 16 + n0 + ne;
      const float4 xv =
          *reinterpret_cast<const float4*>(&xs[n * XST + d4 * 4]);
      const float4 pA = *reinterpret_cast<const float4*>(&pa[n * 8]);
      const float4 pB = *reinterpret_cast<const float4*>(&pa[n * 8 + 4]);
      acc[0][0] = fmaf(pA.x, xv.x, acc[0][0]);
      acc[0][1] = fmaf(pA.x, xv.y, acc[0][1]);
      acc[0][2] = fmaf(pA.x, xv.z, acc[0][2]);
      acc[0][3] = fmaf(pA.x, xv.w, acc[0][3]);
      acc[1][0] = fmaf(pA.y, xv.x, acc[1][0]);
      acc[1][1] = fmaf(pA.y, xv.y, acc[1][1]);
      acc[1][2] = fmaf(pA.y, xv.z, acc[1][2]);
      acc[1][3] = fmaf(pA.y, xv.w, acc[1][3]);
      acc[2][0] = fmaf(pA.z, xv.x, acc[2][0]);
      acc[2][1] = fmaf(pA.z, xv.y, acc[2][1]);
      acc[2][2] = fmaf(pA.z, xv.z, acc[2][2]);
      acc[2][3] = fmaf(pA.z, xv.w, acc[2][3]);
      acc[3][0] = fmaf(pA.w, xv.x, acc[3][0]);
      acc[3][1] = fmaf(pA.w, xv.y, acc[3][1]);
      acc[3][2] = fmaf(pA.w, xv.z, acc[3][2]);
      acc[3][3] = fmaf(pA.w, xv.w, acc[3][3]);
      acc[4][0] = fmaf(pB.x, xv.x, acc[4][0]);
      acc[4][1] = fmaf(pB.x, xv.y, acc[4][1]);
      acc[4][2] = fmaf(pB.x, xv.z, acc[4][2]);
      acc[4][3] = fmaf(pB.x, xv.w, acc[4][3]);
      acc[5][0] = fmaf(pB.y, xv.x, acc[5][0]);
      acc[5][1] = fmaf(pB.y, xv.y, acc[5][1]);
      acc[5][2] = fmaf(pB.y, xv.z, acc[5][2]);
      acc[5][3] = fmaf(pB.y, xv.w, acc[5][3]);
      acc[6][0] = fmaf(pB.z, xv.x, acc[6][0]);
      acc[6][1] = fmaf(pB.z, xv.y, acc[6][1]);
      acc[6][2] = fmaf(pB.z, xv.z, acc[6][2]);
      acc[6][3] = fmaf(pB.z, xv.w, acc[6][3]);
    }
  }

  // ---- flush (once per block) ----
  // combine n-residue partials: lanes with same d4 across ne
#pragma unroll
  for (int s = 0; s < 7; ++s)
#pragma unroll
    for (int i = 0; i < 4; ++i) {
      acc[s][i] += __shfl_xor(acc[s][i], 16);
      acc[s][i] += __shfl_xor(acc[s][i], 32);
    }
  __syncthreads();  // all P2 reads of xs done; reuse as scratch
  float* scr = xs;  // [4][7][16][4]
  if (ne == 0) {
#pragma unroll
    for (int s = 0; s < 7; ++s) {
      const float4 v = {acc[s][0], acc[s][1], acc[s][2], acc[s][3]};
      *reinterpret_cast<float4*>(&scr[((w * 7 + s) * 16 + d4) * 4]) = v;
    }
  }
  __syncthreads();
  {
    const int d = lane;
    float v0 = 0.f;
#pragma unroll
    for (int ww = 0; ww < 4; ++ww)
      v0 += scr[((ww * 7 + w) * 16 + (d >> 2)) * 4 + (d & 3)];
    atomicAdd(&ACC[(b * 8 + w) * 64 + d], v0);
    if (w < 3) {
      float v1 = 0.f;
#pragma unroll
      for (int ww = 0; ww < 4; ++ww)
        v1 += scr[((ww * 7 + w + 4) * 16 + (d >> 2)) * 4 + (d & 3)];
      atomicAdd(&ACC[(b * 8 + w + 4) * 64 + d], v1);
    }
  }
  float zv = 0.f;
#pragma unroll
  for (int s = 0; s < 7; ++s) {
    const float z = wsum64(zac[s]) * 0.25f;  // undo 4x quad replication
    if (lane == s) zv = z;
  }
  if (lane < 7) atomicAdd(&Zg[b * 8 + lane], zv);
}

extern "C" void kernel_launch(void* const* d_in, const int* in_sizes, int n_in,
                              void* d_out, int out_size, void* d_ws,
                              size_t ws_size, hipStream_t stream) {
  const float* inputs     = (const float*)d_in[0];
  const float* slots_init = (const float*)d_in[1];
  const float* slots_mu   = (const float*)d_in[2];
  const float* slots_lsig = (const float*)d_in[3];
  const float* ln_in_g    = (const float*)d_in[4];
  const float* ln_in_b    = (const float*)d_in[5];
  const float* ln_slot_g  = (const float*)d_in[6];
  const float* ln_slot_b  = (const float*)d_in[7];
  const float* ln_mlp_g   = (const float*)d_in[8];
  const float* ln_mlp_b   = (const float*)d_in[9];
  const float* Wq   = (const float*)d_in[10];
  const float* Wk   = (const float*)d_in[11];
  const float* Wv   = (const float*)d_in[12];
  const float* W_ih = (const float*)d_in[13];
  const float* W_hh = (const float*)d_in[14];
  const float* b_ih = (const float*)d_in[15];
  const float* b_hh = (const float*)d_in[16];
  const float* W1   = (const float*)d_in[17];
  const float* b1   = (const float*)d_in[18];
  const float* W2   = (const float*)d_in[19];
  const float* b2   = (const float*)d_in[20];

  float* ws    = (float*)d_ws;
  float* slots = ws;            // B*S*64 = 7168
  float* gqk   = ws + 7168;     // B*8*64 = 8192
  float* sc    = gqk + 8192;    // B*8*2  = 256
  float* ACC   = sc + 256;      // B*8*64 = 8192
  float* Zg    = ACC + 8192;    // B*8    = 128

  float* out = (float*)d_out;

#define SLOT_ARGS                                                          \
  slots_init, slots_mu, slots_lsig, ln_slot_g, ln_slot_b, ln_mlp_g,        \
      ln_mlp_b, ln_in_g, ln_in_b, Wq, Wk, Wv, W_ih, W_hh, b_ih, b_hh, W1,  \
      b1, W2, b2, slots, gqk, sc, ACC, Zg, out

  k_slot<<<112, 64, 0, stream>>>(0, SLOT_ARGS);
  for (int it = 0; it < 3; ++it) {
    k_main<<<BB * BPB, 256, 0, stream>>>(inputs, gqk, sc, ACC, Zg);
    k_slot<<<112, 64, 0, stream>>>(it == 2 ? 2 : 1, SLOT_ARGS);
  }
#undef SLOT_ARGS
}

// Round 5
// 244.842 us; speedup vs baseline: 1.7898x; 1.7898x over previous
//
#include <hip/hip_runtime.h>

#define BB 16
#define NN 38400
#define SS 7
#define TROWS 64   // rows per tile
#define BPB 120    // blocks per batch
#define TPBK 5     // tiles per block (600 tiles / 120 blocks)

__device__ __forceinline__ float wsum64(float v) {
#pragma unroll
  for (int off = 32; off > 0; off >>= 1) v += __shfl_xor(v, off);
  return v;
}

// ---------------------------------------------------------------------------
// Slot-side kernel: 112 blocks (one per (b,s)), 64 threads (lane = d).
// mode 0: init slots; mode 1: GRU+MLP update; mode 2: update + write out.
// ACCM is recovered from ACC: sum_n p*rstd*mean = (1/64) * sum_d ACC[s][d].
// ---------------------------------------------------------------------------
__global__ __launch_bounds__(64) void k_slot(
    int mode,
    const float* __restrict__ slots_init, const float* __restrict__ mu,
    const float* __restrict__ lsig,
    const float* __restrict__ ln_slot_g, const float* __restrict__ ln_slot_b,
    const float* __restrict__ ln_mlp_g, const float* __restrict__ ln_mlp_b,
    const float* __restrict__ ln_in_g, const float* __restrict__ ln_in_b,
    const float* __restrict__ Wq, const float* __restrict__ Wk,
    const float* __restrict__ Wv,
    const float* __restrict__ W_ih, const float* __restrict__ W_hh,
    const float* __restrict__ b_ih, const float* __restrict__ b_hh,
    const float* __restrict__ W1, const float* __restrict__ b1,
    const float* __restrict__ W2, const float* __restrict__ b2,
    float* __restrict__ slots, float* __restrict__ gqk,
    float* __restrict__ sc,
    float* __restrict__ ACC, float* __restrict__ Zg,
    float* __restrict__ out)
{
  const int bs = blockIdx.x;
  const int b = bs / SS, s = bs % SS;
  const int d = threadIdx.x;
  __shared__ float t0[64], t1[64], hh[128];

  float slot;
  if (mode == 0) {
    slot = mu[d] + __expf(lsig[d]) * slots_init[bs * 64 + d];
  } else {
    const float zv = Zg[b * 8 + s];
    const float ac = ACC[(b * 8 + s) * 64 + d];
    const float am = wsum64(ac) * (1.f / 64.f);  // = sum_n p*rstd*mean
    const float ubar = (ln_in_g[d] * (ac - am) + ln_in_b[d] * zv) / zv;
    t0[d] = ubar;
    __syncthreads();
    float upd = 0.f;
#pragma unroll
    for (int e = 0; e < 64; ++e) upd += t0[e] * Wv[d * 64 + e];
    const float sp = slots[bs * 64 + d];
    __syncthreads();
    t0[d] = upd;
    t1[d] = sp;
    __syncthreads();
    float s_r = b_ih[d] + b_hh[d];
    float s_z = b_ih[64 + d] + b_hh[64 + d];
    float i_n = b_ih[128 + d];
    float h_n = b_hh[128 + d];
#pragma unroll
    for (int e = 0; e < 64; ++e) {
      const float u = t0[e], p = t1[e];
      s_r += u * W_ih[d * 64 + e] + p * W_hh[d * 64 + e];
      s_z += u * W_ih[(64 + d) * 64 + e] + p * W_hh[(64 + d) * 64 + e];
      i_n += u * W_ih[(128 + d) * 64 + e];
      h_n += p * W_hh[(128 + d) * 64 + e];
    }
    const float rg = 1.f / (1.f + __expf(-s_r));
    const float zg = 1.f / (1.f + __expf(-s_z));
    const float ng = tanhf(i_n + rg * h_n);
    const float hv = (1.f - zg) * ng + zg * sp;
    const float mn = wsum64(hv) * (1.f / 64.f);
    const float dv = hv - mn;
    const float vr = wsum64(dv * dv) * (1.f / 64.f);
    const float rs = rsqrtf(vr + 1e-5f);
    const float mld = dv * rs * ln_mlp_g[d] + ln_mlp_b[d];
    __syncthreads();
    t0[d] = mld;
    __syncthreads();
    float h0 = b1[d], h1 = b1[64 + d];
#pragma unroll
    for (int e = 0; e < 64; ++e) {
      const float m = t0[e];
      h0 += m * W1[d * 64 + e];
      h1 += m * W1[(64 + d) * 64 + e];
    }
    hh[d] = fmaxf(h0, 0.f);
    hh[64 + d] = fmaxf(h1, 0.f);
    __syncthreads();
    float o = hv + b2[d];
#pragma unroll
    for (int j = 0; j < 128; ++j) o += hh[j] * W2[d * 128 + j];
    slot = o;
  }

  if (mode == 2) {
    out[bs * 64 + d] = slot;
    return;
  }
  slots[bs * 64 + d] = slot;

  // tail: LN_slot -> q -> gqk (scale & ln_in_g folded), sgq, cb
  const float mn = wsum64(slot) * (1.f / 64.f);
  const float dv = slot - mn;
  const float vr = wsum64(dv * dv) * (1.f / 64.f);
  const float rs = rsqrtf(vr + 1e-5f);
  const float sln = dv * rs * ln_slot_g[d] + ln_slot_b[d];
  __syncthreads();
  t0[d] = sln;
  __syncthreads();
  float qv = 0.f;
#pragma unroll
  for (int e = 0; e < 64; ++e) qv += t0[e] * Wq[d * 64 + e];
  __syncthreads();
  t1[d] = qv;
  __syncthreads();
  float qe = 0.f;
#pragma unroll
  for (int dd = 0; dd < 64; ++dd) qe += t1[dd] * Wk[dd * 64 + d];
  qe *= 0.125f;  // scale = D^-0.5
  const float gq = ln_in_g[d] * qe;
  gqk[(b * 8 + s) * 64 + d] = gq;
  const float sg = wsum64(gq);
  const float cb = wsum64(ln_in_b[d] * qe);
  if (d == 0) {
    sc[(b * 8 + s) * 2 + 0] = sg;
    sc[(b * 8 + s) * 2 + 1] = cb;
  }
  ACC[(b * 8 + s) * 64 + d] = 0.f;
  if (d == 0) Zg[b * 8 + s] = 0.f;
}

// ---------------------------------------------------------------------------
// Main kernel: 1920 blocks (120/batch) x 256 threads, 5 consecutive 64-row
// tiles per block. NO x staging in LDS — both phases read x coalesced from
// global (phase 2 is an L1/L2 hit on the 16KB just fetched).
//   P1: quad-per-row (thread owns 16 cols, 4 coalesced float4 loads):
//       7 dots vs LDS-broadcast gqk + LN stats, 2-step shfl_xor quad
//       reduce, softmax; q==0 writes p*rstd to pa[row][8].
//   P2: thread = (row-group rg, chunk d4): 4 coalesced float4 x re-reads
//       (issued BEFORE the barrier to hide latency under it) + broadcast
//       pa reads; 28 fma/row into persistent acc[7][4].
// One flush per block (shfl + LDS scratch), 448 + 28 atomics.
// ---------------------------------------------------------------------------
__global__ __launch_bounds__(256, 4) void k_main(
    const float* __restrict__ x,
    const float* __restrict__ gqk,  // [B][8][64]
    const float* __restrict__ sc,   // [B][8][2]
    float* __restrict__ ACC, float* __restrict__ Zg)
{
  __shared__ __align__(16) float qbs[512];        // 2 KB
  __shared__ __align__(16) float pa[TROWS * 8];   // 2 KB
  __shared__ __align__(16) float scr[4 * 7 * 16 * 4];  // 7 KB
  __shared__ float scs[16];

  const int t = threadIdx.x;
  const int lane = t & 63;
  const int w = t >> 6;
  const int b = blockIdx.x / BPB;
  const int kb = blockIdx.x % BPB;

  qbs[t] = gqk[b * 512 + t];
  qbs[t + 256] = gqk[b * 512 + 256 + t];
  if (t < 16) scs[t] = sc[b * 16 + t];

  float acc[7][4];
#pragma unroll
  for (int s = 0; s < 7; ++s)
#pragma unroll
    for (int i = 0; i < 4; ++i) acc[s][i] = 0.f;
  float zac[7] = {0, 0, 0, 0, 0, 0, 0};

  const int r1 = t >> 2, q1 = t & 3;  // P1: row, quad-lane
  const int rg = t >> 4, d4 = t & 15; // P2: row-group, col chunk

  const float* xb = x + (size_t)b * NN * 64;
  __syncthreads();  // qbs/scs ready

  for (int ti = 0; ti < TPBK; ++ti) {
    const int row0 = (kb * TPBK + ti) * TROWS;

    // ---- phase 1: quad-per-row, direct coalesced global reads ----
    {
      const float* xq = xb + (size_t)(row0 + r1) * 64 + q1 * 16;
      const float4 v0 = *reinterpret_cast<const float4*>(xq);
      const float4 v1 = *reinterpret_cast<const float4*>(xq + 4);
      const float4 v2 = *reinterpret_cast<const float4*>(xq + 8);
      const float4 v3 = *reinterpret_cast<const float4*>(xq + 12);

      float lg[7] = {0, 0, 0, 0, 0, 0, 0};
      float sum = 0.f, sq = 0.f;
      const float4 vv[4] = {v0, v1, v2, v3};
#pragma unroll
      for (int j = 0; j < 4; ++j) {
        const float4 v = vv[j];
        sum += v.x + v.y + v.z + v.w;
        sq = fmaf(v.x, v.x, fmaf(v.y, v.y, fmaf(v.z, v.z, fmaf(v.w, v.w, sq))));
#pragma unroll
        for (int s = 0; s < 7; ++s) {
          const float4 g = *reinterpret_cast<const float4*>(
              &qbs[s * 64 + q1 * 16 + j * 4]);
          lg[s] = fmaf(v.x, g.x,
                       fmaf(v.y, g.y, fmaf(v.z, g.z, fmaf(v.w, g.w, lg[s]))));
        }
      }
      // quad reduce (offsets 1,2 stay within the 4-lane group)
#pragma unroll
      for (int off = 1; off <= 2; off <<= 1) {
        sum += __shfl_xor(sum, off);
        sq += __shfl_xor(sq, off);
#pragma unroll
        for (int s = 0; s < 7; ++s) lg[s] += __shfl_xor(lg[s], off);
      }
      const float mean = sum * (1.f / 64.f);
      const float var = sq * (1.f / 64.f) - mean * mean;
      const float rstd = rsqrtf(var + 1e-5f);
      const float rm = rstd * mean;
      float mx = -1e30f;
#pragma unroll
      for (int s = 0; s < 7; ++s) {
        lg[s] = rstd * lg[s] - rm * scs[s * 2] + scs[s * 2 + 1];
        mx = fmaxf(mx, lg[s]);
      }
      float se = 0.f;
#pragma unroll
      for (int s = 0; s < 7; ++s) {
        lg[s] = __expf(lg[s] - mx);
        se += lg[s];
      }
      const float inv = 1.f / se;
      float pr[7];
#pragma unroll
      for (int s = 0; s < 7; ++s) {
        const float p = lg[s] * inv + 1e-8f;
        pr[s] = p * rstd;
        zac[s] += p;  // 4x quad-replicated; corrected at flush
      }
      if (q1 == 0) {
        const float4 w1 = {pr[0], pr[1], pr[2], pr[3]};
        const float4 w2 = {pr[4], pr[5], pr[6], 0.f};
        *reinterpret_cast<float4*>(&pa[r1 * 8]) = w1;
        *reinterpret_cast<float4*>(&pa[r1 * 8 + 4]) = w2;
      }
    }

    // issue P2 global loads BEFORE the barrier (L1-hot; latency hides)
    const float* xc = xb + (size_t)(row0 + rg) * 64 + d4 * 4;
    const float4 x0 = *reinterpret_cast<const float4*>(xc);
    const float4 x1 = *reinterpret_cast<const float4*>(xc + 16 * 64);
    const float4 x2 = *reinterpret_cast<const float4*>(xc + 32 * 64);
    const float4 x3 = *reinterpret_cast<const float4*>(xc + 48 * 64);
    __syncthreads();  // pa ready

    // ---- phase 2: 28 fma per row into persistent registers ----
    const float4 xv[4] = {x0, x1, x2, x3};
#pragma unroll
    for (int i = 0; i < 4; ++i) {
      const int n = rg + 16 * i;
      const float4 pA = *reinterpret_cast<const float4*>(&pa[n * 8]);
      const float4 pB = *reinterpret_cast<const float4*>(&pa[n * 8 + 4]);
      const float4 v = xv[i];
      acc[0][0] = fmaf(pA.x, v.x, acc[0][0]);
      acc[0][1] = fmaf(pA.x, v.y, acc[0][1]);
      acc[0][2] = fmaf(pA.x, v.z, acc[0][2]);
      acc[0][3] = fmaf(pA.x, v.w, acc[0][3]);
      acc[1][0] = fmaf(pA.y, v.x, acc[1][0]);
      acc[1][1] = fmaf(pA.y, v.y, acc[1][1]);
      acc[1][2] = fmaf(pA.y, v.z, acc[1][2]);
      acc[1][3] = fmaf(pA.y, v.w, acc[1][3]);
      acc[2][0] = fmaf(pA.z, v.x, acc[2][0]);
      acc[2][1] = fmaf(pA.z, v.y, acc[2][1]);
      acc[2][2] = fmaf(pA.z, v.z, acc[2][2]);
      acc[2][3] = fmaf(pA.z, v.w, acc[2][3]);
      acc[3][0] = fmaf(pA.w, v.x, acc[3][0]);
      acc[3][1] = fmaf(pA.w, v.y, acc[3][1]);
      acc[3][2] = fmaf(pA.w, v.z, acc[3][2]);
      acc[3][3] = fmaf(pA.w, v.w, acc[3][3]);
      acc[4][0] = fmaf(pB.x, v.x, acc[4][0]);
      acc[4][1] = fmaf(pB.x, v.y, acc[4][1]);
      acc[4][2] = fmaf(pB.x, v.z, acc[4][2]);
      acc[4][3] = fmaf(pB.x, v.w, acc[4][3]);
      acc[5][0] = fmaf(pB.y, v.x, acc[5][0]);
      acc[5][1] = fmaf(pB.y, v.y, acc[5][1]);
      acc[5][2] = fmaf(pB.y, v.z, acc[5][2]);
      acc[5][3] = fmaf(pB.y, v.w, acc[5][3]);
      acc[6][0] = fmaf(pB.z, v.x, acc[6][0]);
      acc[6][1] = fmaf(pB.z, v.y, acc[6][1]);
      acc[6][2] = fmaf(pB.z, v.z, acc[6][2]);
      acc[6][3] = fmaf(pB.z, v.w, acc[6][3]);
    }
    __syncthreads();  // P2 pa reads done before next tile overwrites
  }

  // ---- flush (once per block) ----
  // combine the 4 row-residues within each wave (same d4 across rg)
#pragma unroll
  for (int s = 0; s < 7; ++s)
#pragma unroll
    for (int i = 0; i < 4; ++i) {
      acc[s][i] += __shfl_xor(acc[s][i], 16);
      acc[s][i] += __shfl_xor(acc[s][i], 32);
    }
  if ((lane >> 4) == 0) {  // lanes 0..15 of each wave, d4 = lane
#pragma unroll
    for (int s = 0; s < 7; ++s) {
      const float4 v = {acc[s][0], acc[s][1], acc[s][2], acc[s][3]};
      *reinterpret_cast<float4*>(&scr[((w * 7 + s) * 16 + lane) * 4]) = v;
    }
  }
  __syncthreads();
  {
    const int d = lane;
    float v0 = 0.f;
#pragma unroll
    for (int ww = 0; ww < 4; ++ww)
      v0 += scr[((ww * 7 + w) * 16 + (d >> 2)) * 4 + (d & 3)];
    atomicAdd(&ACC[(b * 8 + w) * 64 + d], v0);
    if (w < 3) {
      float v1 = 0.f;
#pragma unroll
      for (int ww = 0; ww < 4; ++ww)
        v1 += scr[((ww * 7 + w + 4) * 16 + (d >> 2)) * 4 + (d & 3)];
      atomicAdd(&ACC[(b * 8 + w + 4) * 64 + d], v1);
    }
  }
  float zv = 0.f;
#pragma unroll
  for (int s = 0; s < 7; ++s) {
    const float z = wsum64(zac[s]) * 0.25f;  // undo 4x quad replication
    if (lane == s) zv = z;
  }
  if (lane < 7) atomicAdd(&Zg[b * 8 + lane], zv);
}

extern "C" void kernel_launch(void* const* d_in, const int* in_sizes, int n_in,
                              void* d_out, int out_size, void* d_ws,
                              size_t ws_size, hipStream_t stream) {
  const float* inputs     = (const float*)d_in[0];
  const float* slots_init = (const float*)d_in[1];
  const float* slots_mu   = (const float*)d_in[2];
  const float* slots_lsig = (const float*)d_in[3];
  const float* ln_in_g    = (const float*)d_in[4];
  const float* ln_in_b    = (const float*)d_in[5];
  const float* ln_slot_g  = (const float*)d_in[6];
  const float* ln_slot_b  = (const float*)d_in[7];
  const float* ln_mlp_g   = (const float*)d_in[8];
  const float* ln_mlp_b   = (const float*)d_in[9];
  const float* Wq   = (const float*)d_in[10];
  const float* Wk   = (const float*)d_in[11];
  const float* Wv   = (const float*)d_in[12];
  const float* W_ih = (const float*)d_in[13];
  const float* W_hh = (const float*)d_in[14];
  const float* b_ih = (const float*)d_in[15];
  const float* b_hh = (const float*)d_in[16];
  const float* W1   = (const float*)d_in[17];
  const float* b1   = (const float*)d_in[18];
  const float* W2   = (const float*)d_in[19];
  const float* b2   = (const float*)d_in[20];

  float* ws    = (float*)d_ws;
  float* slots = ws;            // B*S*64 = 7168
  float* gqk   = ws + 7168;     // B*8*64 = 8192
  float* sc    = gqk + 8192;    // B*8*2  = 256
  float* ACC   = sc + 256;      // B*8*64 = 8192
  float* Zg    = ACC + 8192;    // B*8    = 128

  float* out = (float*)d_out;

#define SLOT_ARGS                                                          \
  slots_init, slots_mu, slots_lsig, ln_slot_g, ln_slot_b, ln_mlp_g,        \
      ln_mlp_b, ln_in_g, ln_in_b, Wq, Wk, Wv, W_ih, W_hh, b_ih, b_hh, W1,  \
      b1, W2, b2, slots, gqk, sc, ACC, Zg, out

  k_slot<<<112, 64, 0, stream>>>(0, SLOT_ARGS);
  for (int it = 0; it < 3; ++it) {
    k_main<<<BB * BPB, 256, 0, stream>>>(inputs, gqk, sc, ACC, Zg);
    k_slot<<<112, 64, 0, stream>>>(it == 2 ? 2 : 1, SLOT_ARGS);
  }
#undef SLOT_ARGS
}